// Round 1
// baseline (336.580 us; speedup 1.0000x reference)
//
#include <hip/hip_runtime.h>

// spatial_encoding_block: B=65536, C=105, H=W=3
//   nearest-fill (mask from x[0,0,:,:]) -> depthwise 2x2 conv + bias
//   -> LeakyReLU(0.2) -> max over 2x2 -> + filled center -> [B,C] out.
// Memory-bound: ~248 MB in + ~27.5 MB out => ~44 us floor at 6.3 TB/s.

#define NC 105

__global__ __launch_bounds__(256) void se_kernel(const float* __restrict__ x,
                                                 const float* __restrict__ w,
                                                 const float* __restrict__ b,
                                                 float* __restrict__ out) {
    // 256 threads * 9 floats = 2304 floats staged per block
    __shared__ float sx[2304];
    __shared__ int s_near[9];

    const int tid = threadIdx.x;
    const long long base = (long long)blockIdx.x * 2304;

    // ---- coalesced global->LDS staging (float4; 2304*4 B block base is 16B aligned) ----
    float4* sx4 = (float4*)sx;
    const float4* x4 = (const float4*)(x + base);
    sx4[tid]       = x4[tid];
    sx4[tid + 256] = x4[tid + 256];
    if (tid < 64) sx4[tid + 512] = x4[tid + 512];

    // ---- nearest-fill map from x[0,0,:,:] (global mask; once per block) ----
    if (tid == 0) {
        float m0[9];
        #pragma unroll
        for (int p = 0; p < 9; ++p) m0[p] = x[p];
        bool mask[9];
        #pragma unroll
        for (int p = 0; p < 9; ++p) mask[p] = (m0[p] == 0.0f);
        #pragma unroll
        for (int p = 0; p < 9; ++p) {
            int np = p;
            if (mask[p]) {
                int best = 0x7fffffff, bq = 0;
                const int pi = p / 3, pj = p % 3;
                for (int q = 0; q < 9; ++q) {
                    if (mask[q]) continue;             // exclude zero pixels as sources
                    const int qi = q / 3, qj = q % 3;
                    const int d = (pi - qi) * (pi - qi) + (pj - qj) * (pj - qj);
                    if (d < best) { best = d; bq = q; } // ties -> lowest flat index
                }
                np = bq;
            }
            s_near[p] = np;
        }
    }
    __syncthreads();

    const int idx = blockIdx.x * 256 + tid;  // = b*105 + c
    const int c   = idx % NC;

    // LDS reads at stride 9 floats: odd stride -> 2 lanes/bank (free)
    const float* a = &sx[tid * 9];
    float v[9];
    #pragma unroll
    for (int p = 0; p < 9; ++p) v[p] = a[s_near[p]];

    const float w0 = w[c * 4 + 0], w1 = w[c * 4 + 1];
    const float w2 = w[c * 4 + 2], w3 = w[c * 4 + 3];
    const float bias = b[c];

    // depthwise 2x2 VALID conv on the filled 3x3 tile
    float y00 = fmaf(v[0], w0, fmaf(v[1], w1, fmaf(v[3], w2, v[4] * w3))) + bias;
    float y01 = fmaf(v[1], w0, fmaf(v[2], w1, fmaf(v[4], w2, v[5] * w3))) + bias;
    float y10 = fmaf(v[3], w0, fmaf(v[4], w1, fmaf(v[6], w2, v[7] * w3))) + bias;
    float y11 = fmaf(v[4], w0, fmaf(v[5], w1, fmaf(v[7], w2, v[8] * w3))) + bias;

    // LeakyReLU(0.2)
    y00 = (y00 > 0.0f) ? y00 : 0.2f * y00;
    y01 = (y01 > 0.0f) ? y01 : 0.2f * y01;
    y10 = (y10 > 0.0f) ? y10 : 0.2f * y10;
    y11 = (y11 > 0.0f) ? y11 : 0.2f * y11;

    const float m = fmaxf(fmaxf(y00, y01), fmaxf(y10, y11));
    out[idx] = m + v[4];   // + aug[:,:,1,1]
}

extern "C" void kernel_launch(void* const* d_in, const int* in_sizes, int n_in,
                              void* d_out, int out_size, void* d_ws, size_t ws_size,
                              hipStream_t stream) {
    const float* x = (const float*)d_in[0];
    const float* w = (const float*)d_in[1];
    const float* b = (const float*)d_in[2];
    float* out = (float*)d_out;

    const int n_bc = in_sizes[0] / 9;      // B*C = 6,881,280
    const int grid = n_bc / 256;           // 26880 exactly (B*C divisible by 256)

    se_kernel<<<grid, 256, 0, stream>>>(x, w, b, out);
}